// Round 11
// baseline (278.611 us; speedup 1.0000x reference)
//
#include <hip/hip_runtime.h>
#include <hip/hip_bf16.h>

// Problem constants (B=2, S=2048, D=2048, NH=32, NKV=8, HD=64, NREP=4)
#define S_LEN 2048
#define DMODEL 2048
#define N_H 32
#define N_KV 8
#define H_D 64
#define ROWS 4096   // B*S
#define QKV_LD 3072 // fused qkv row stride: q[0:2048) k[2048:2560) v[2560:3072)

typedef __bf16 bf16x8 __attribute__((ext_vector_type(8)));
typedef float f32x4 __attribute__((ext_vector_type(4)));

// fp32 -> bf16 raw bits, round-to-nearest-even
static __device__ __forceinline__ unsigned short f2bf(float f) {
  unsigned int u = __float_as_uint(f);
  u += 0x7FFFu + ((u >> 16) & 1u);
  return (unsigned short)(u >> 16);
}
static __device__ __forceinline__ float bf2f(unsigned short s) {
  return __uint_as_float((unsigned int)s << 16);
}

// async global->LDS, 16 B per lane. LDS dest = wave-uniform base + lane*16.
static __device__ __forceinline__ void async16(const void* g, void* l) {
  __builtin_amdgcn_global_load_lds(
      (const __attribute__((address_space(1))) unsigned int*)g,
      (__attribute__((address_space(3))) unsigned int*)l, 16, 0, 0);
}

// counted vmcnt + raw barrier (T4): loads stay in flight across the barrier.
#define VMB(N)                                                    \
  do {                                                            \
    asm volatile("s_waitcnt vmcnt(" #N ")" ::: "memory");         \
    __builtin_amdgcn_s_barrier();                                 \
    asm volatile("" ::: "memory");                                \
  } while (0)

// ---------------------------------------------------------------------------
// fp32 -> bf16 bulk convert (8 elems/thread) — fallback path only
// ---------------------------------------------------------------------------
__global__ __launch_bounds__(256) void cvt_bf16_k(
    const float* __restrict__ in, unsigned short* __restrict__ out) {
  const size_t i = ((size_t)blockIdx.x * 256 + threadIdx.x) * 8;
  const float4 a = *(const float4*)&in[i];
  const float4 b = *(const float4*)&in[i + 4];
  union { unsigned short u[8]; uint4 v; } p;
  p.u[0] = f2bf(a.x); p.u[1] = f2bf(a.y); p.u[2] = f2bf(a.z); p.u[3] = f2bf(a.w);
  p.u[4] = f2bf(b.x); p.u[5] = f2bf(b.y); p.u[6] = f2bf(b.z); p.u[7] = f2bf(b.w);
  *(uint4*)&out[i] = p.v;
}

// ---------------------------------------------------------------------------
// Combined prep: z=0..3 transpose fp32 weights -> bf16 wqkvT/woT blocks;
// z=4: straight cvt x fp32 -> xb bf16 (64x64 blocks x 256 thr x 8 elems).
// ---------------------------------------------------------------------------
__global__ __launch_bounds__(256) void prep_all_k(
    const float* __restrict__ x, const float* __restrict__ wq,
    const float* __restrict__ wk, const float* __restrict__ wv,
    const float* __restrict__ wo, unsigned short* __restrict__ xb,
    unsigned short* __restrict__ wqkvT, unsigned short* __restrict__ woT) {
  const int z = blockIdx.z;
  if (z == 4) {
    const size_t i =
        (((size_t)blockIdx.y * 64 + blockIdx.x) * 256 + threadIdx.x) * 8;
    const float4 a = *(const float4*)&x[i];
    const float4 b = *(const float4*)&x[i + 4];
    union { unsigned short u[8]; uint4 v; } p;
    p.u[0] = f2bf(a.x); p.u[1] = f2bf(a.y); p.u[2] = f2bf(a.z); p.u[3] = f2bf(a.w);
    p.u[4] = f2bf(b.x); p.u[5] = f2bf(b.y); p.u[6] = f2bf(b.z); p.u[7] = f2bf(b.w);
    *(uint4*)&xb[i] = p.v;
    return;
  }
  const float* in;
  unsigned short* out;
  int C;
  if (z == 0)      { in = wq; out = wqkvT;                  C = 2048; }
  else if (z == 1) { in = wk; out = wqkvT + 2048ull * 2048; C = 512;  }
  else if (z == 2) { in = wv; out = wqkvT + 2560ull * 2048; C = 512;  }
  else             { in = wo; out = woT;                    C = 2048; }
  if (blockIdx.x * 32 >= C) return;

  __shared__ unsigned short tile[32][33];
  const int tx = threadIdx.x & 31;
  const int ty = threadIdx.x >> 5;
  const int r0 = blockIdx.y * 32;  // K rows of input
  const int c0 = blockIdx.x * 32;  // C cols of input
#pragma unroll
  for (int i = 0; i < 32; i += 8)
    tile[ty + i][tx] = f2bf(in[(size_t)(r0 + ty + i) * C + c0 + tx]);
  __syncthreads();
#pragma unroll
  for (int i = 0; i < 32; i += 8)
    out[(size_t)(c0 + ty + i) * 2048 + r0 + tx] = tile[tx][ty + i];
}

// log2(e) / sqrt(HD): softmax base-2 conversion + 1/sqrt(d), folded into q
#define SCALE_LOG2E 0.18033688011112042f

// ---------------------------------------------------------------------------
// Fused RoPE (blocks 0..20479) + v->vT transpose (blocks 20480..22527).
// ---------------------------------------------------------------------------
__global__ __launch_bounds__(256) void rope_vt_k(
    unsigned short* __restrict__ qkv, unsigned short* __restrict__ vT,
    const float* __restrict__ fc, const float* __restrict__ fs) {
  const int blk = blockIdx.x;
  if (blk < 20480) {
    const int PQ = ROWS * N_H * (H_D / 2);   // 4194304
    const int PK = ROWS * N_KV * (H_D / 2);  // 1048576
    const int idx = blk * 256 + threadIdx.x;
    if (idx >= PQ + PK) return;
    unsigned short* base;
    float c, sn;
    bool isq;
    if (idx < PQ) {
      const int i = idx & 31;
      const int h = (idx >> 5) & 31;
      const int row = idx >> 10;
      const int s = row & (S_LEN - 1);
      c = fc[s * 32 + i];
      sn = fs[s * 32 + i];
      base = qkv + (size_t)row * QKV_LD + h * H_D + 2 * i;
      isq = true;
    } else {
      const int p = idx - PQ;
      const int i = p & 31;
      const int h = (p >> 5) & 7;
      const int row = p >> 8;
      const int s = row & (S_LEN - 1);
      c = fc[s * 32 + i];
      sn = fs[s * 32 + i];
      base = qkv + (size_t)row * QKV_LD + 2048 + h * H_D + 2 * i;
      isq = false;
    }
    const float x0 = bf2f(base[0]);
    const float x1 = bf2f(base[1]);
    const float sc = isq ? SCALE_LOG2E : 1.0f;
    base[0] = f2bf((x0 * c - x1 * sn) * sc);
    base[1] = f2bf((x0 * sn + x1 * c) * sc);
  } else {
    __shared__ unsigned short tile[32][33];
    const int t = blk - 20480;        // 0..2047
    const int bx = t & 15;            // C/32 = 16
    const int by = t >> 4;            // R/32 = 128
    const unsigned short* in = qkv + 2560;
    const int tx = threadIdx.x & 31;
    const int ty = threadIdx.x >> 5;
    const int r0 = by * 32;
    const int c0 = bx * 32;
#pragma unroll
    for (int i = 0; i < 32; i += 8)
      tile[ty + i][tx] = in[(size_t)(r0 + ty + i) * QKV_LD + c0 + tx];
    __syncthreads();
#pragma unroll
    for (int i = 0; i < 32; i += 8)
      vT[(size_t)(c0 + ty + i) * ROWS + r0 + tx] = tile[tx][ty + i];
  }
}

// ---------------------------------------------------------------------------
// gemm8w: 8-phase deep-pipelined BM=256 x BN=192 MFMA GEMM (T2+T3+T4+T5).
// Verified round 9 (QKV path). Ledger in round-9 comments.
// ---------------------------------------------------------------------------
template <int STORE_BF16>
__global__ __launch_bounds__(512, 2) void gemm8w_bt_k(
    const unsigned short* __restrict__ A, const unsigned short* __restrict__ BT,
    void* __restrict__ Cp, int M, int N, int K, int lda) {
  __shared__ __align__(16) unsigned short As[2][2][128 * 64];
  __shared__ __align__(16) unsigned short Bs[2][192 * 64];
  const int tid = threadIdx.x;
  const int wave = tid >> 6;
  const int lane = tid & 63;
  const int quad = lane >> 4;
  const int l16 = lane & 15;
  const int nwg = gridDim.x * gridDim.y;
  const int flat = blockIdx.y * gridDim.x + blockIdx.x;
  const int swz = (flat & 7) * (nwg >> 3) + (flat >> 3);
  const int m0 = (swz % gridDim.x) * 256;
  const int n0 = (swz / gridDim.x) * 192;
  const int ah = wave & 1;         // A half this wave computes on
  const int ag = wave >> 1;        // stage slot within A-group
  const int wn = (wave >> 1) * 48; // per-wave 48-col N strip
  const int rx = (l16 & 7) << 3;
  const int scol = ((lane & 7) * 8) ^ ((lane >> 3) << 3);
  const int srA = 8 * ag + (lane >> 3);
  const int srB = 8 * wave + (lane >> 3);
  const size_t abase = (size_t)(m0 + ah * 128) * lda;
  const size_t bbase = (size_t)n0 * K;
  f32x4 acc[8][3] = {};

#define STG_B(j, buf, kt)                                             \
  async16(&BT[bbase + (size_t)(64 * (j) + srB) * K + (kt) + scol],    \
          &Bs[buf][(64 * (j) + 8 * wave) * 64])
#define STG_A(j, buf, kt)                                             \
  async16(&A[abase + (size_t)(32 * (j) + srA) * lda + (kt) + scol],   \
          &As[buf][ah][(32 * (j) + 8 * ag) * 64])

  // prologue: stage tile 0 into buf 0 in ledger order
  STG_B(0, 0, 0); STG_B(1, 0, 0); STG_B(2, 0, 0);
  STG_A(0, 0, 0); STG_A(1, 0, 0); STG_A(2, 0, 0); STG_A(3, 0, 0);

  const int NT = K >> 6;
  for (int t = 0; t < NT; ++t) {
    const int cur = t & 1, nxt = cur ^ 1;
    const int ktn = (t + 1 < NT) ? ((t + 1) << 6) : 0;
    const unsigned short* Ac = &As[cur][ah][0];
    const unsigned short* Bc = &Bs[cur][0];
    bf16x8 bf[3][2];

    // ---- phase 0: B frags + A frags 0,1 ----
    VMB(3);
    {
      bf16x8 af[2][2];
#pragma unroll
      for (int n = 0; n < 3; n++)
#pragma unroll
        for (int kk = 0; kk < 2; kk++)
          bf[n][kk] = *(const bf16x8*)&Bc[(wn + n * 16 + l16) * 64 +
                                          ((kk * 32 + quad * 8) ^ rx)];
#pragma unroll
      for (int i = 0; i < 2; i++)
#pragma unroll
        for (int kk = 0; kk < 2; kk++)
          af[i][kk] = *(const bf16x8*)&Ac[((0 + i) * 16 + l16) * 64 +
                                          ((kk * 32 + quad * 8) ^ rx)];
      STG_B(0, nxt, ktn); STG_B(1, nxt, ktn);
      __builtin_amdgcn_s_setprio(1);
#pragma unroll
      for (int i = 0; i < 2; i++)
#pragma unroll
        for (int n = 0; n < 3; n++)
#pragma unroll
          for (int kk = 0; kk < 2; kk++)
            acc[0 + i][n] = __builtin_amdgcn_mfma_f32_16x16x32_bf16(
                af[i][kk], bf[n][kk], acc[0 + i][n], 0, 0, 0);
      __builtin_amdgcn_s_setprio(0);
    }

    // ---- phase 1: A frags 2,3 ----
    VMB(4);
    {
      bf16x8 af[2][2];
#pragma unroll
      for (int i = 0; i < 2; i++)
#pragma unroll
        for (int kk = 0; kk < 2; kk++)
          af[i][kk] = *(const bf16x8*)&Ac[((2 + i) * 16 + l16) * 64 +
                                          ((kk * 32 + quad * 8) ^ rx)];
      STG_B(2, nxt, ktn); STG_A(0, nxt, ktn);
      __builtin_amdgcn_s_setprio(1);
#pragma unroll
      for (int i = 0; i < 2; i++)
#pragma unroll
        for (int n = 0; n < 3; n++)
#pragma unroll
          for (int kk = 0; kk < 2; kk++)
            acc[2 + i][n] = __builtin_amdgcn_mfma_f32_16x16x32_bf16(
                af[i][kk], bf[n][kk], acc[2 + i][n], 0, 0, 0);
      __builtin_amdgcn_s_setprio(0);
    }

    // ---- phase 2: A frags 4,5 ----
    VMB(5);
    {
      bf16x8 af[2][2];
#pragma unroll
      for (int i = 0; i < 2; i++)
#pragma unroll
        for (int kk = 0; kk < 2; kk++)
          af[i][kk] = *(const bf16x8*)&Ac[((4 + i) * 16 + l16) * 64 +
                                          ((kk * 32 + quad * 8) ^ rx)];
      STG_A(1, nxt, ktn); STG_A(2, nxt, ktn);
      __builtin_amdgcn_s_setprio(1);
#pragma unroll
      for (int i = 0; i < 2; i++)
#pragma unroll
        for (int n = 0; n < 3; n++)
#pragma unroll
          for (int kk = 0; kk < 2; kk++)
            acc[4 + i][n] = __builtin_amdgcn_mfma_f32_16x16x32_bf16(
                af[i][kk], bf[n][kk], acc[4 + i][n], 0, 0, 0);
      __builtin_amdgcn_s_setprio(0);
    }

    // ---- phase 3: A frags 6,7 ----
    VMB(6);
    {
      bf16x8 af[2][2];
#pragma unroll
      for (int i = 0; i < 2; i++)
#pragma unroll
        for (int kk = 0; kk < 2; kk++)
          af[i][kk] = *(const bf16x8*)&Ac[((6 + i) * 16 + l16) * 64 +
                                          ((kk * 32 + quad * 8) ^ rx)];
      STG_A(3, nxt, ktn);
      __builtin_amdgcn_s_setprio(1);
#pragma unroll
      for (int i = 0; i < 2; i++)
#pragma unroll
        for (int n = 0; n < 3; n++)
#pragma unroll
          for (int kk = 0; kk < 2; kk++)
            acc[6 + i][n] = __builtin_amdgcn_mfma_f32_16x16x32_bf16(
                af[i][kk], bf[n][kk], acc[6 + i][n], 0, 0, 0);
      __builtin_amdgcn_s_setprio(0);
    }
  }
#undef STG_A
#undef STG_B

  // Epilogue: C/D layout col = lane&15, row = quad*4 + reg  [m89/m91]
#pragma unroll
  for (int f = 0; f < 8; f++) {
#pragma unroll
    for (int e = 0; e < 4; e++) {
      const int mrow = m0 + ah * 128 + f * 16 + quad * 4 + e;
#pragma unroll
      for (int n = 0; n < 3; n++) {
        const int ncol = n0 + wn + n * 16 + l16;
        const float val = acc[f][n][e];
        if (STORE_BF16) {
          ((unsigned short*)Cp)[(size_t)mrow * N + ncol] = f2bf(val);
        } else {
          ((float*)Cp)[(size_t)mrow * N + ncol] = val;
        }
      }
    }
  }
}

// ---------------------------------------------------------------------------
// gemm8n: 8-phase GEMM, BM=256 x BN=128 variant (verified round 8, WO path).
// ---------------------------------------------------------------------------
template <int STORE_BF16>
__global__ __launch_bounds__(512, 2) void gemm8n_bt_k(
    const unsigned short* __restrict__ A, const unsigned short* __restrict__ BT,
    void* __restrict__ Cp, int M, int N, int K, int lda) {
  __shared__ __align__(16) unsigned short As[2][2][128 * 64];
  __shared__ __align__(16) unsigned short Bs[2][128 * 64];
  const int tid = threadIdx.x;
  const int wave = tid >> 6;
  const int lane = tid & 63;
  const int quad = lane >> 4;
  const int l16 = lane & 15;
  const int nwg = gridDim.x * gridDim.y;
  const int flat = blockIdx.y * gridDim.x + blockIdx.x;
  const int swz = (flat & 7) * (nwg >> 3) + (flat >> 3);
  const int m0 = (swz % gridDim.x) * 256;
  const int n0 = (swz / gridDim.x) * 128;
  const int ah = wave & 1;
  const int ag = wave >> 1;
  const int wn = (wave >> 1) * 32;    // per-wave N strip (0,32,64,96)
  const int rx = (l16 & 7) << 3;
  const int scol = ((lane & 7) * 8) ^ ((lane >> 3) << 3);
  const int srA = 8 * ag + (lane >> 3);
  const int srB = 8 * wave + (lane >> 3);  // B row within 64-row group
  const size_t abase = (size_t)(m0 + ah * 128) * lda;
  const size_t bbase = (size_t)n0 * K;
  f32x4 acc[8][2] = {};

#define STG_B(j, buf, kt)                                             \
  async16(&BT[bbase + (size_t)(64 * (j) + srB) * K + (kt) + scol],    \
          &Bs[buf][(64 * (j) + 8 * wave) * 64])
#define STG_A(j, buf, kt)                                             \
  async16(&A[abase + (size_t)(32 * (j) + srA) * lda + (kt) + scol],   \
          &As[buf][ah][(32 * (j) + 8 * ag) * 64])

  STG_B(0, 0, 0); STG_B(1, 0, 0);
  STG_A(0, 0, 0); STG_A(1, 0, 0); STG_A(2, 0, 0); STG_A(3, 0, 0);

  const int NT = K >> 6;
  for (int t = 0; t < NT; ++t) {
    const int cur = t & 1, nxt = cur ^ 1;
    const int ktn = (t + 1 < NT) ? ((t + 1) << 6) : 0;
    const unsigned short* Ac = &As[cur][ah][0];
    const unsigned short* Bc = &Bs[cur][0];
    bf16x8 bf[2][2];

    VMB(3);
    {
      bf16x8 af[2][2];
#pragma unroll
      for (int n = 0; n < 2; n++)
#pragma unroll
        for (int kk = 0; kk < 2; kk++)
          bf[n][kk] = *(const bf16x8*)&Bc[(wn + n * 16 + l16) * 64 +
                                          ((kk * 32 + quad * 8) ^ rx)];
#pragma unroll
      for (int i = 0; i < 2; i++)
#pragma unroll
        for (int kk = 0; kk < 2; kk++)
          af[i][kk] = *(const bf16x8*)&Ac[((0 + i) * 16 + l16) * 64 +
                                          ((kk * 32 + quad * 8) ^ rx)];
      STG_B(0, nxt, ktn); STG_B(1, nxt, ktn);
      __builtin_amdgcn_s_setprio(1);
#pragma unroll
      for (int i = 0; i < 2; i++)
#pragma unroll
        for (int n = 0; n < 2; n++)
#pragma unroll
          for (int kk = 0; kk < 2; kk++)
            acc[0 + i][n] = __builtin_amdgcn_mfma_f32_16x16x32_bf16(
                af[i][kk], bf[n][kk], acc[0 + i][n], 0, 0, 0);
      __builtin_amdgcn_s_setprio(0);
    }

    VMB(4);
    {
      bf16x8 af[2][2];
#pragma unroll
      for (int i = 0; i < 2; i++)
#pragma unroll
        for (int kk = 0; kk < 2; kk++)
          af[i][kk] = *(const bf16x8*)&Ac[((2 + i) * 16 + l16) * 64 +
                                          ((kk * 32 + quad * 8) ^ rx)];
      STG_A(0, nxt, ktn); STG_A(1, nxt, ktn);
      __builtin_amdgcn_s_setprio(1);
#pragma unroll
      for (int i = 0; i < 2; i++)
#pragma unroll
        for (int n = 0; n < 2; n++)
#pragma unroll
          for (int kk = 0; kk < 2; kk++)
            acc[2 + i][n] = __builtin_amdgcn_mfma_f32_16x16x32_bf16(
                af[i][kk], bf[n][kk], acc[2 + i][n], 0, 0, 0);
      __builtin_amdgcn_s_setprio(0);
    }

    VMB(5);
    {
      bf16x8 af[2][2];
#pragma unroll
      for (int i = 0; i < 2; i++)
#pragma unroll
        for (int kk = 0; kk < 2; kk++)
          af[i][kk] = *(const bf16x8*)&Ac[((4 + i) * 16 + l16) * 64 +
                                          ((kk * 32 + quad * 8) ^ rx)];
      STG_A(2, nxt, ktn); STG_A(3, nxt, ktn);
      __builtin_amdgcn_s_setprio(1);
#pragma unroll
      for (int i = 0; i < 2; i++)
#pragma unroll
        for (int n = 0; n < 2; n++)
#pragma unroll
          for (int kk = 0; kk < 2; kk++)
            acc[4 + i][n] = __builtin_amdgcn_mfma_f32_16x16x32_bf16(
                af[i][kk], bf[n][kk], acc[4 + i][n], 0, 0, 0);
      __builtin_amdgcn_s_setprio(0);
    }

    VMB(6);
    {
      bf16x8 af[2][2];
#pragma unroll
      for (int i = 0; i < 2; i++)
#pragma unroll
        for (int kk = 0; kk < 2; kk++)
          af[i][kk] = *(const bf16x8*)&Ac[((6 + i) * 16 + l16) * 64 +
                                          ((kk * 32 + quad * 8) ^ rx)];
      __builtin_amdgcn_s_setprio(1);
#pragma unroll
      for (int i = 0; i < 2; i++)
#pragma unroll
        for (int n = 0; n < 2; n++)
#pragma unroll
          for (int kk = 0; kk < 2; kk++)
            acc[6 + i][n] = __builtin_amdgcn_mfma_f32_16x16x32_bf16(
                af[i][kk], bf[n][kk], acc[6 + i][n], 0, 0, 0);
      __builtin_amdgcn_s_setprio(0);
    }
  }
#undef STG_A
#undef STG_B

#pragma unroll
  for (int f = 0; f < 8; f++) {
#pragma unroll
    for (int e = 0; e < 4; e++) {
      const int mrow = m0 + ah * 128 + f * 16 + quad * 4 + e;
#pragma unroll
      for (int n = 0; n < 2; n++) {
        const int ncol = n0 + wn + n * 16 + l16;
        const float val = acc[f][n][e];
        if (STORE_BF16) {
          ((unsigned short*)Cp)[(size_t)mrow * N + ncol] = f2bf(val);
        } else {
          ((float*)Cp)[(size_t)mrow * N + ncol] = val;
        }
      }
    }
  }
}

// ---------------------------------------------------------------------------
// Fallback MFMA GEMM (round-4): C[M][N] = A[M][K] @ B[K][N], B fp32 native.
// ---------------------------------------------------------------------------
template <int AF32, int STORE_BF16>
__global__ __launch_bounds__(256) void gemm_k(
    const void* __restrict__ Ap, const float* __restrict__ B,
    void* __restrict__ Cp, int M, int N, int K) {
  constexpr int LDP = 40;
  __shared__ __align__(16) unsigned short As[128 * LDP];
  __shared__ __align__(16) unsigned short Bs[128 * LDP];
  const int tid = threadIdx.x;
  const int wave = tid >> 6;
  const int lane = tid & 63;
  const int quad = lane >> 4;
  const int l16 = lane & 15;
  const int m0 = blockIdx.x * 128;
  const int n0 = blockIdx.y * 128;
  const int wm = (wave >> 1) * 64;
  const int wn = (wave & 1) * 64;
  f32x4 acc[4][4] = {};

  for (int kt = 0; kt < K; kt += 32) {
    __syncthreads();
    if (AF32) {
      const float* A = (const float*)Ap;
      for (int c = tid; c < 1024; c += 256) {
        const int r = c >> 3;
        const int cc = (c & 7) << 2;
        const float4 w = *(const float4*)&A[(size_t)(m0 + r) * K + kt + cc];
        union { unsigned short u[4]; uint2 v; } p;
        p.u[0] = f2bf(w.x); p.u[1] = f2bf(w.y);
        p.u[2] = f2bf(w.z); p.u[3] = f2bf(w.w);
        *(uint2*)&As[r * LDP + cc] = p.v;
      }
    } else {
      const unsigned short* A = (const unsigned short*)Ap;
      for (int c = tid; c < 512; c += 256) {
        const int r = c >> 2;
        const int cc = (c & 3) << 3;
        *(uint4*)&As[r * LDP + cc] =
            *(const uint4*)&A[(size_t)(m0 + r) * K + kt + cc];
      }
    }
    for (int c = tid; c < 1024; c += 256) {
      const int kr = c >> 5;
      const int nc = (c & 31) << 2;
      const float4 w = *(const float4*)&B[(size_t)(kt + kr) * N + n0 + nc];
      Bs[(nc + 0) * LDP + kr] = f2bf(w.x);
      Bs[(nc + 1) * LDP + kr] = f2bf(w.y);
      Bs[(nc + 2) * LDP + kr] = f2bf(w.z);
      Bs[(nc + 3) * LDP + kr] = f2bf(w.w);
    }
    __syncthreads();
    bf16x8 af[4], bfr[4];
#pragma unroll
    for (int i = 0; i < 4; i++)
      af[i] = *(const bf16x8*)&As[(wm + i * 16 + l16) * LDP + quad * 8];
#pragma unroll
    for (int j = 0; j < 4; j++)
      bfr[j] = *(const bf16x8*)&Bs[(wn + j * 16 + l16) * LDP + quad * 8];
#pragma unroll
    for (int i = 0; i < 4; i++)
#pragma unroll
      for (int j = 0; j < 4; j++)
        acc[i][j] =
            __builtin_amdgcn_mfma_f32_16x16x32_bf16(af[i], bfr[j], acc[i][j], 0, 0, 0);
  }
#pragma unroll
  for (int i = 0; i < 4; i++) {
#pragma unroll
    for (int e = 0; e < 4; e++) {
      const int mrow = m0 + wm + i * 16 + quad * 4 + e;
#pragma unroll
      for (int j = 0; j < 4; j++) {
        const int ncol = n0 + wn + j * 16 + l16;
        const float val = acc[i][j][e];
        if (STORE_BF16) {
          ((unsigned short*)Cp)[(size_t)mrow * N + ncol] = f2bf(val);
        } else {
          ((float*)Cp)[(size_t)mrow * N + ncol] = val;
        }
      }
    }
  }
}

// ---------------------------------------------------------------------------
// Fallback RoPE (separate q/k buffers)
// ---------------------------------------------------------------------------
__global__ __launch_bounds__(256) void rope_k(
    unsigned short* __restrict__ q, unsigned short* __restrict__ kk,
    const float* __restrict__ fc, const float* __restrict__ fs,
    int qstride, int kstride) {
  const int PQ = ROWS * N_H * (H_D / 2);
  const int PK = ROWS * N_KV * (H_D / 2);
  const int idx = blockIdx.x * 256 + threadIdx.x;
  if (idx >= PQ + PK) return;
  unsigned short* base;
  float c, sn;
  if (idx < PQ) {
    const int i = idx & 31;
    const int h = (idx >> 5) & 31;
    const int row = idx >> 10;
    const int s = row & (S_LEN - 1);
    c = fc[s * 32 + i];
    sn = fs[s * 32 + i];
    base = q + (size_t)row * qstride + h * H_D + 2 * i;
  } else {
    const int p = idx - PQ;
    const int i = p & 31;
    const int h = (p >> 5) & 7;
    const int row = p >> 8;
    const int s = row & (S_LEN - 1);
    c = fc[s * 32 + i];
    sn = fs[s * 32 + i];
    base = kk + (size_t)row * kstride + h * H_D + 2 * i;
  }
  const float x0 = bf2f(base[0]);
  const float x1 = bf2f(base[1]);
  base[0] = f2bf(x0 * c - x1 * sn);
  base[1] = f2bf(x0 * sn + x1 * c);
}

// ---------------------------------------------------------------------------
// attn v14 = v13 + T15 double-pipeline: PV(t-1) issues alongside QK(t), so
// the exp2->pack->LDS-roundtrip chain of tile t overlaps PV MFMA of t-1 and
// gets a full iteration of slack (kernel measured latency-bound: VALU 54%,
// MFMA 23% — no pipe saturated).
//  - Vt triple-buffered (PV(t-1) reads (t-1)%3 while staging writes (t+1)%3
//    in the same barrier interval; all three indices distinct for all t).
//    Ks stays double-buffered (QK(t) is same-iteration).
//  - carried pf[2] (P fragments of t-1) costs ~10 VGPR -> launch_bounds
//    (512,2): cap 128 VGPR (<=128 still allows 16 waves/CU); LDS 56 KB
//    -> 2 blocks/CU unchanged.
//  - per-tile body (swapped S^T QK, XOR swizzle, perm pack, uniform mask
//    branch, ones-MFMA l) byte-identical to verified v13.
// ---------------------------------------------------------------------------
__global__ __launch_bounds__(512, 2) void attn_mfma14_k(
    const unsigned short* __restrict__ qkv, const unsigned short* __restrict__ vT,
    unsigned short* __restrict__ ao) {
  const int pair = blockIdx.x, h = blockIdx.y, b = blockIdx.z;
  const int hk = h >> 2;
  const int tid = threadIdx.x;
  const int wave = tid >> 6;      // 0..7
  const int l16 = tid & 15;
  const int quad = (tid & 63) >> 4;
  const int rr = tid >> 3;        // 0..63 staging row
  const int dc = (tid & 7) * 8;   // staging 8-elem (16B) chunk
  const int rx = (l16 & 7) << 3;  // read/P-side XOR (elem units)
  const int sx = (rr & 7) << 3;   // stage-side XOR

  __shared__ __align__(16) unsigned short Ks[2][64 * 64];  // [key][d] swz
  __shared__ __align__(16) unsigned short Vt[3][64 * 64];  // [d][key] swz, 3-buf
  __shared__ __align__(16) unsigned short Ps[8][16 * 64];  // wave-private swz

  bf16x8 ones;
#pragma unroll
  for (int j = 0; j < 8; j++) ones[j] = (__bf16)1.0f;

  const size_t kbase =
      (size_t)(b * S_LEN) * QKV_LD + 2048 + hk * H_D + dc;  // k cols
  const size_t vbase = (size_t)(hk * H_D + rr) * ROWS + b * S_LEN + dc;

  for (int sel = 0; sel < 2; ++sel) {
    const int qb = sel ? (15 - pair) : pair;  // q-block of 128 rows
    const int row0 = qb * 128;
    const int ktiles = 2 * qb + 2;

    // Q fragments: A/B-frag layout lane holds [l16][quad*8+j]; 16 rows/wave
    bf16x8 af[2];
    {
      const size_t qrow = (size_t)(b * S_LEN + row0 + wave * 16 + l16);
#pragma unroll
      for (int c = 0; c < 2; c++)
        af[c] =
            *(const bf16x8*)&qkv[qrow * QKV_LD + h * H_D + c * 32 + quad * 8];
    }

    f32x4 o_acc[4] = {};
    f32x4 l_acc = {};
    bf16x8 pf[2];  // carried P fragments of tile kt-1

    // Prefetch tile 0 into registers, then stage into buffers 0.
    uint4 rk, rv;
    {
      rk = *(const uint4*)&qkv[kbase + (size_t)rr * QKV_LD];
      rv = *(const uint4*)&vT[vbase];
    }
    __syncthreads();  // prior-sel readers of LDS done before overwrite
    *(uint4*)&Ks[0][rr * 64 + (dc ^ sx)] = rk;
    *(uint4*)&Vt[0][rr * 64 + (dc ^ sx)] = rv;

    int vprev = 2, vnxt = 1;  // (kt-1)%3 (invalid at kt=0), (kt+1)%3
    for (int kt = 0; kt < ktiles; ++kt) {
      // Prefetch next tile while this tile computes.
      if (kt + 1 < ktiles) {
        rk = *(const uint4*)&qkv[kbase + (size_t)((kt + 1) * 64 + rr) * QKV_LD];
        rv = *(const uint4*)&vT[vbase + (size_t)(kt + 1) * 64];
      }
      __syncthreads();  // staging of tile kt complete (all waves)

      // QK^T(kt): D[row=k(quad*4+e), col=q(l16)] = mfma(K-frag, Q-frag).
      f32x4 sacc[4];
      {
        const unsigned short* Kc = &Ks[kt & 1][0];
#pragma unroll
        for (int n = 0; n < 4; n++) {
          f32x4 z = {};
#pragma unroll
          for (int c = 0; c < 2; c++) {
            const bf16x8 bk = *(const bf16x8*)&Kc[(n * 16 + l16) * 64 +
                                                  ((c * 32 + quad * 8) ^ rx)];
            z = __builtin_amdgcn_mfma_f32_16x16x32_bf16(bk, af[c], z, 0, 0, 0);
          }
          sacc[n] = z;
        }
      }

      // PV(kt-1) + l(kt-1): independent of QK(kt); overlaps exp2(kt) slack.
      if (kt > 0) {
        const unsigned short* Vc = &Vt[vprev][0];
#pragma unroll
        for (int c = 0; c < 2; c++)
          l_acc = __builtin_amdgcn_mfma_f32_16x16x32_bf16(pf[c], ones, l_acc,
                                                          0, 0, 0);
#pragma unroll
        for (int n = 0; n < 4; n++)
#pragma unroll
          for (int c = 0; c < 2; c++) {
            const bf16x8 bv = *(const bf16x8*)&Vc[(n * 16 + l16) * 64 +
                                                  ((c * 32 + quad * 8) ^ rx)];
            o_acc[n] = __builtin_amdgcn_mfma_f32_16x16x32_bf16(pf[c], bv,
                                                               o_acc[n], 0, 0, 0);
          }
      }

      // pe = exp2(s); truncate to bf16 (v_perm pack); masked -> 0.
      const bool maybe_mask = (kt >= 2 * qb);
      {
        const int prow = l16 * 64;
        if (maybe_mask) {
          const int krel0 = (kt - 2 * qb) * 64;
          const int qn = wave * 16 + l16;  // relative q row of this lane
#pragma unroll
          for (int n = 0; n < 4; n++) {
            const int kb0 = krel0 + n * 16 + quad * 4;  // relative k of e=0
            float pe[4];
#pragma unroll
            for (int e = 0; e < 4; e++) {
              float v = exp2f(sacc[n][e]);
              if (kb0 + e > qn) v = 0.f;
              pe[e] = v;
            }
            uint2 u;
            u.x = __builtin_amdgcn_perm(__float_as_uint(pe[1]),
                                        __float_as_uint(pe[0]), 0x07060302u);
            u.y = __builtin_amdgcn_perm(__float_as_uint(pe[3]),
                                        __float_as_uint(pe[2]), 0x07060302u);
            *(uint2*)&Ps[wave][prow + ((n * 16 + quad * 4) ^ rx)] = u;
          }
        } else {
#pragma unroll
          for (int n = 0; n < 4; n++) {
            float pe[4];
#pragma unroll
            for (int e = 0; e < 4; e++) pe[e] = exp2f(sacc[n][e]);
            uint2 u;
            u.x = __builtin_amdgcn_perm(__float_as_uint(pe[1]),
                                        __float_as_uint(pe[0]), 0x07060302u);
            u.y = __builtin_amdgcn_perm(__float_as_uint(pe[3]),
                                        __float_as_uint(pe[2]), 0x07060302u);
            *(uint2*)&Ps[wave][prow + ((n * 16 + quad * 4) ^ rx)] = u;
          }
        }
      }
      // wave-private Ps: compiler inserts lgkmcnt wait; no barrier needed.
      // Load the NEW carried fragments (overwrites pf after PV used old ones).
#pragma unroll
      for (int c = 0; c < 2; c++)
        pf[c] = *(const bf16x8*)&Ps[wave][l16 * 64 +
                                          ((c * 32 + quad * 8) ^ rx)];

      // Stage prefetched tile kt+1 (Ks[(kt+1)&1], Vt[(kt+1)%3]); neither
      // aliases Ks[kt&1] (QK this iter) nor Vt[(kt-1)%3] (PV this iter).
      if (kt + 1 < ktiles) {
        *(uint4*)&Ks[(kt + 1) & 1][rr * 64 + (dc ^ sx)] = rk;
        *(uint4*)&Vt[vnxt][rr * 64 + (dc ^ sx)] = rv;
      }
      vprev = (vprev == 2) ? 0 : vprev + 1;  // = kt%3 for next iter
      vnxt = (vnxt == 2) ? 0 : vnxt + 1;     // = (kt+2)%3 for next iter
    }

    // Flush PV of the final tile (pf holds P(ktiles-1); vprev == (ktiles-1)%3).
    {
      const unsigned short* Vc = &Vt[vprev][0];
#pragma unroll
      for (int c = 0; c < 2; c++)
        l_acc = __builtin_amdgcn_mfma_f32_16x16x32_bf16(pf[c], ones, l_acc,
                                                        0, 0, 0);
#pragma unroll
      for (int n = 0; n < 4; n++)
#pragma unroll
        for (int c = 0; c < 2; c++) {
          const bf16x8 bv = *(const bf16x8*)&Vc[(n * 16 + l16) * 64 +
                                                ((c * 32 + quad * 8) ^ rx)];
          o_acc[n] = __builtin_amdgcn_mfma_f32_16x16x32_bf16(pf[c], bv,
                                                             o_acc[n], 0, 0, 0);
        }
    }

    // Epilogue: l already reduced by MFMA; normalize, store bf16 (in-place q).
#pragma unroll
    for (int e = 0; e < 4; e++) {
      const float inv = 1.f / l_acc[e];
      const size_t row =
          (size_t)(b * S_LEN + row0 + wave * 16 + quad * 4 + e);
#pragma unroll
      for (int n = 0; n < 4; n++)
        ao[row * QKV_LD + h * H_D + n * 16 + l16] = f2bf(o_acc[n][e] * inv);
    }
  }
}

#define LK 72  // padded inner stride for fallback attention

// ---------------------------------------------------------------------------
// Round-4 attention (fallback path only): k/v separate buffers stride 512.
// ---------------------------------------------------------------------------
__global__ __launch_bounds__(256) void attn_mfma_k(
    const unsigned short* __restrict__ q, const unsigned short* __restrict__ k,
    const unsigned short* __restrict__ v, unsigned short* __restrict__ ao) {
  const int qt = blockIdx.x, h = blockIdx.y, b = blockIdx.z;
  const int hk = h >> 2;
  const int tid = threadIdx.x;
  const int wave = tid >> 6;
  const int l16 = tid & 15;
  const int quad = (tid & 63) >> 4;

  __shared__ __align__(16) unsigned short Ks[64 * LK];
  __shared__ __align__(16) unsigned short Vt[64 * LK];
  __shared__ __align__(16) unsigned short Ps[64 * LK];

  bf16x8 af[2];
  {
    const size_t qrow = (size_t)(b * S_LEN + qt * 64 + wave * 16 + l16);
#pragma unroll
    for (int c = 0; c < 2; c++)
      af[c] = *(const bf16x8*)&q[qrow * DMODEL + h * H_D + c * 32 + quad * 8];
  }

  f32x4 o_acc[4] = {};
  float m_i[4], l_i[4];
#pragma unroll
  for (int e = 0; e < 4; e++) { m_i[e] = -INFINITY; l_i[e] = 0.f; }

  for (int kt = 0; kt <= qt; ++kt) {
    const int kb = kt * 64;
    __syncthreads();
    {
      const int kr = tid >> 2;
      const int dc = (tid & 3) * 16;
      const size_t gro = (size_t)(b * S_LEN + kb + kr) * (N_KV * H_D) + hk * H_D + dc;
      *(uint4*)&Ks[kr * LK + dc] = *(const uint4*)&k[gro];
      *(uint4*)&Ks[kr * LK + dc + 8] = *(const uint4*)&k[gro + 8];
      union { unsigned short u[8]; uint4 v; } w0, w1;
      w0.v = *(const uint4*)&v[gro];
      w1.v = *(const uint4*)&v[gro + 8];
#pragma unroll
      for (int j = 0; j < 8; j++) Vt[(dc + j) * LK + kr] = w0.u[j];
#pragma unroll
      for (int j = 0; j < 8; j++) Vt[(dc + 8 + j) * LK + kr] = w1.u[j];
    }
    __syncthreads();

    f32x4 sacc[4];
#pragma unroll
    for (int n = 0; n < 4; n++) {
      f32x4 z = {};
#pragma unroll
      for (int c = 0; c < 2; c++) {
        const bf16x8 bk = *(const bf16x8*)&Ks[(n * 16 + l16) * LK + c * 32 + quad * 8];
        z = __builtin_amdgcn_mfma_f32_16x16x32_bf16(af[c], bk, z, 0, 0, 0);
      }
      sacc[n] = z;
    }

    float p[4][4], mnew[4];
#pragma unroll
    for (int e = 0; e < 4; e++) mnew[e] = m_i[e];
#pragma unroll
    for (int n = 0; n < 4; n++)
#pragma unroll
      for (int e = 0; e < 4; e++) {
        float s = sacc[n][e] * 0.125f;
        if (kt == qt && (n * 16 + l16) > (wave * 16 + quad * 4 + e))
          s = -INFINITY;
        p[n][e] = s;
        mnew[e] = fmaxf(mnew[e], s);
      }
#pragma unroll
    for (int e = 0; e < 4; e++) {
      mnew[e] = fmaxf(mnew[e], __shfl_xor(mnew[e], 1));
      mnew[e] = fmaxf(mnew[e], __shfl_xor(mnew[e], 2));
      mnew[e] = fmaxf(mnew[e], __shfl_xor(mnew[e], 4));
      mnew[e] = fmaxf(mnew[e], __shfl_xor(mnew[e], 8));
      const float alpha = __expf(m_i[e] - mnew[e]);
      m_i[e] = mnew[e];
      l_i[e] *= alpha;
#pragma unroll
      for (int n = 0; n < 4; n++) o_acc[n][e] *= alpha;
    }
#pragma unroll
    for (int n = 0; n < 4; n++)
#pragma unroll
      for (int e = 0; e < 4; e++) {
        const float pe = __expf(p[n][e] - m_i[e]);
        p[n][e] = pe;
        l_i[e] += pe;
      }

#pragma unroll
    for (int n = 0; n < 4; n++)
#pragma unroll
      for (int e = 0; e < 4; e++)
        Ps[(wave * 16 + quad * 4 + e) * LK + n * 16 + l16] = f2bf(p[n][e]);
    __syncthreads();

    bf16x8 pf[2];
#pragma unroll
    for (int c = 0; c < 2; c++)
      pf[c] = *(const bf16x8*)&Ps[(wave * 16 + l16) * LK + c * 32 + quad * 8];
#pragma unroll
    for (int n = 0; n < 4; n++)
#pragma unroll
      for (int c = 0; c < 2; c++) {
        const bf16x8 bv = *(const bf16x8*)&Vt[(n * 16 + l16) * LK + c * 32 + quad * 8];
        o_acc[n] = __builtin_amdgcn_mfma_f32_16x16x32_bf16(pf[c], bv, o_acc[n], 0, 0, 0);
      }
  }

#pragma unroll
  for (int e = 0; e < 4; e++) {
    l_i[e] += __shfl_xor(l_i[e], 1);
    l_i[e] += __shfl_xor(l_i[e], 2);
    l_i[e] += __shfl_xor(l_i[e], 4);
    l_i[e] += __shfl_xor(l_i[e], 8);
    const float inv = 1.f / l_i[e];
    const size_t row = (size_t)(b * S_LEN + qt * 64 + wave * 16 + quad * 4 + e);
#pragma unroll
    for (int n = 0; n < 4; n++)
      ao[row * DMODEL + h * H_D + n * 16 + l16] = f2bf(o_acc[n][e] * inv);
  }
}

// ---------------------------------------------------------------------------
extern "C" void kernel_launch(void* const* d_in, const int* in_sizes, int n_in,
                              void* d_out, int out_size, void* d_ws, size_t ws_size,
                              hipStream_t stream) {
  const float* x = (const float*)d_in[0];
  const float* fc = (const float*)d_in[1];
  const float* fs = (const float*)d_in[2];
  const float* wq = (const float*)d_in[3];
  const float* wk = (const float*)d_in[4];
  const float* wv = (const float*)d_in[5];
  const float* wo = (const float*)d_in[6];

  char* ws = (char*)d_ws;
  const dim3 b256(256);

  if (ws_size >= (64ull << 20)) {
    // Fast path (64 MB):
    //   qkv   bf16 [4096][3072] @ 0     (24 MB)  q|k|v fused; attn out in q cols
    //   xb    bf16 [4096][2048] @ 24 MB (16 MB)
    //   wqkvT bf16 [3072][2048] @ 40 MB (12 MB)
    //   woT   bf16 [2048][2048] @ 52 MB ( 8 MB)
    //   vT    bf16 [ 512][4096] @ 60 MB ( 4 MB)
    unsigned short* qkv = (unsigned short*)(ws);
    unsigned short* xb = (unsigned short*)(ws + (24ull << 20));
    unsigned short* wqkvT = (unsigned short*)(ws + (40ull << 20));
    unsigned short* woT = (unsigned short*)(ws + (52ull << 20));
    unsigned short* vT = (unsigned short*)(ws + (60ull << 20));

    prep_all_k<<<dim3(64, 64, 5), b256, 0, stream>>>(x, wq, wk, wv, wo, xb,
                                                     wqkvT, woT);

    // Fused QKV projection, 8-phase 256x192: grid (16,16) = 256 blocks = 1/CU
    gemm8w_bt_k<1><<<dim3(16, 16), dim3(512), 0, stream>>>(xb, wqkvT, qkv, 4096,
                                                           3072, 2048, 2048);

    // RoPE (q pre-scaled by log2e/8, k plain) + v -> vT transpose, fused
    rope_vt_k<<<dim3(20480 + 2048), b256, 0, stream>>>(qkv, vT, fc, fs);

    // Paired 8-wave attention (v14 = v13 + T15 PV/QK double-pipeline).
    attn_mfma14_k<<<dim3(8, N_H, 2), dim3(512), 0, stream>>>(qkv, vT, qkv);

    // Output projection, 8-phase 256x128 (256 blocks = 1/CU): fp32 d_out
    gemm8n_bt_k<0><<<dim3(16, 16), dim3(512), 0, stream>>>(qkv, woT, d_out,
                                                           4096, 2048, 2048,
                                                           QKV_LD);
  } else {
    // Round-4 fallback (<= 40 MB)
    unsigned short* q = (unsigned short*)(ws);
    unsigned short* k = (unsigned short*)(ws + (16ull << 20));
    unsigned short* v = (unsigned short*)(ws + (20ull << 20));
    unsigned short* xb = (unsigned short*)(ws + (24ull << 20));
    const bool have_xb = ws_size >= (40ull << 20);

    if (have_xb) {
      cvt_bf16_k<<<dim3(ROWS * DMODEL / (256 * 8)), b256, 0, stream>>>(x, xb);
      gemm_k<0, 1><<<dim3(32, 16), b256, 0, stream>>>(xb, wq, q, 4096, 2048, 2048);
      gemm_k<0, 1><<<dim3(32, 4), b256, 0, stream>>>(xb, wk, k, 4096, 512, 2048);
      gemm_k<0, 1><<<dim3(32, 4), b256, 0, stream>>>(xb, wv, v, 4096, 512, 2048);
    } else {
      gemm_k<1, 1><<<dim3(32, 16), b256, 0, stream>>>(x, wq, q, 4096, 2048, 2048);
      gemm_k<1, 1><<<dim3(32, 4), b256, 0, stream>>>(x, wk, k, 4096, 512, 2048);
      gemm_k<1, 1><<<dim3(32, 4), b256, 0, stream>>>(x, wv, v, 4096, 512, 2048);
    }

    rope_k<<<dim3(20480), b256, 0, stream>>>(q, k, fc, fs, N_H * H_D, N_KV * H_D);
    attn_mfma_k<<<dim3(S_LEN / 64, N_H, 2), b256, 0, stream>>>(q, k, v, q);
    gemm_k<0, 0><<<dim3(32, 16), b256, 0, stream>>>(q, wo, d_out, 4096, 2048, 2048);
  }
}